// Round 1
// baseline (142.124 us; speedup 1.0000x reference)
//
#include <hip/hip_runtime.h>
#include <hip/hip_bf16.h>

#define B_ 16
#define T_ 2048
#define C_ 1024
#define HD_ 64

typedef __attribute__((ext_vector_type(8))) short bf16x8;
typedef __attribute__((ext_vector_type(4))) float f32x4;

__device__ __forceinline__ unsigned short f2bf(float f) {
  unsigned int u = __builtin_bit_cast(unsigned int, f);
  unsigned int r = (u + 0x7fffu + ((u >> 16) & 1u)) >> 16;
  return (unsigned short)r;
}

// ---------------- W convert + transpose: wt[m][d][c] = bf16(W_m[c][d]) ----------------
__global__ void wconv_kernel(const float* __restrict__ Wk, const float* __restrict__ Wq,
                             const float* __restrict__ Wv, unsigned short* __restrict__ wt) {
  int o = blockIdx.x * 256 + threadIdx.x;   // 3*64*1024 = 196608 total
  if (o >= 3 * HD_ * C_) return;
  int m = o >> 16;          // /65536
  int d = (o >> 10) & 63;
  int c = o & 1023;
  const float* W = (m == 0) ? Wk : (m == 1) ? Wq : Wv;
  wt[o] = f2bf(W[c * HD_ + d]);
}

// ---------------- QKV projection: [32768,1024] x [1024,64]x3 -> bf16 k,q,v ----------------
__global__ __launch_bounds__(512) void qkv_kernel(const float* __restrict__ x,
                                                  const unsigned short* __restrict__ wt,
                                                  unsigned short* __restrict__ kb,
                                                  unsigned short* __restrict__ qb,
                                                  unsigned short* __restrict__ vb) {
  __shared__ __align__(16) unsigned short x_lds[128 * 72];      // [row][c] padded
  __shared__ __align__(16) unsigned short w_lds[3 * 64 * 72];   // [m][d][c] padded

  const int tid = threadIdx.x;
  const int lane = tid & 63;
  const int w = tid >> 6;          // 8 waves
  const int r0 = blockIdx.x * 128;
  const int l15 = lane & 15;
  const int lh = lane >> 4;

  f32x4 acc[12];
#pragma unroll
  for (int i = 0; i < 12; ++i) acc[i] = {0.f, 0.f, 0.f, 0.f};

  for (int kk = 0; kk < 16; ++kk) {
    const int c0 = kk * 64;
    __syncthreads();
    // stage x tile (128x64 fp32 -> bf16), 2048 float4 chunks
#pragma unroll
    for (int i = 0; i < 4; ++i) {
      int c = i * 512 + tid;
      int row = c >> 4, col4 = c & 15;
      const float4 f = *reinterpret_cast<const float4*>(&x[(size_t)(r0 + row) * C_ + c0 + col4 * 4]);
      ushort4 h;
      h.x = f2bf(f.x); h.y = f2bf(f.y); h.z = f2bf(f.z); h.w = f2bf(f.w);
      *reinterpret_cast<ushort4*>(&x_lds[row * 72 + col4 * 4]) = h;
    }
    // stage W tiles: 3 x 64 rows x 8 chunks of 8 bf16
#pragma unroll
    for (int i = 0; i < 3; ++i) {
      int c = i * 512 + tid;
      int m = c >> 9, rd = (c >> 3) & 63, c8 = c & 7;
      bf16x8 v = *reinterpret_cast<const bf16x8*>(&wt[((m * 64 + rd) << 10) + c0 + c8 * 8]);
      *reinterpret_cast<bf16x8*>(&w_lds[m * 4608 + rd * 72 + c8 * 8]) = v;
    }
    __syncthreads();
#pragma unroll
    for (int ks = 0; ks < 2; ++ks) {
      bf16x8 a = *reinterpret_cast<const bf16x8*>(&x_lds[(w * 16 + l15) * 72 + ks * 32 + lh * 8]);
#pragma unroll
      for (int cf = 0; cf < 12; ++cf) {
        bf16x8 b = *reinterpret_cast<const bf16x8*>(
            &w_lds[(cf >> 2) * 4608 + ((cf & 3) * 16 + l15) * 72 + ks * 32 + lh * 8]);
        acc[cf] = __builtin_amdgcn_mfma_f32_16x16x32_bf16(a, b, acc[cf], 0, 0, 0);
      }
    }
  }
  // epilogue: C/D layout col=lane&15, row=(lane>>4)*4+r
#pragma unroll
  for (int cf = 0; cf < 4; ++cf) {
    int col = cf * 16 + l15;
#pragma unroll
    for (int r = 0; r < 4; ++r) {
      int row = r0 + w * 16 + lh * 4 + r;
      kb[(size_t)row * HD_ + col] = f2bf(acc[cf][r]);
    }
  }
#pragma unroll
  for (int cf = 0; cf < 4; ++cf) {
    int col = cf * 16 + l15;
#pragma unroll
    for (int r = 0; r < 4; ++r) {
      int row = r0 + w * 16 + lh * 4 + r;
      qb[(size_t)row * HD_ + col] = f2bf(acc[4 + cf][r]);
    }
  }
#pragma unroll
  for (int cf = 0; cf < 4; ++cf) {
    int col = cf * 16 + l15;
#pragma unroll
    for (int r = 0; r < 4; ++r) {
      int row = r0 + w * 16 + lh * 4 + r;
      vb[(size_t)row * HD_ + col] = f2bf(acc[8 + cf][r]);
    }
  }
}

// ---------------- flash attention (queries = k rows, keys = q rows) ----------------
__global__ __launch_bounds__(256) void attn_kernel(const unsigned short* __restrict__ kb,
                                                   const unsigned short* __restrict__ qb,
                                                   const unsigned short* __restrict__ vb,
                                                   float* __restrict__ out) {
  __shared__ __align__(16) unsigned short q_lds[64 * 72];  // [s][d] padded
  __shared__ __align__(16) unsigned short v_lds[64 * 72];  // [d][s] padded (transposed)
  __shared__ __align__(16) unsigned short p_lds[64 * 72];  // [t][s] padded

  const int tid = threadIdx.x;
  const int lane = tid & 63;
  const int w = tid >> 6;        // 4 waves x 16 query rows
  const int jt = blockIdx.x;     // t-tile
  const int b = blockIdx.y;
  const int t0 = jt * 64;
  const int l15 = lane & 15;
  const int lh = lane >> 4;
  const size_t base = (size_t)b * T_ * HD_;

  // hoist k fragments (A operand), 2 d-halves
  bf16x8 kf[2];
#pragma unroll
  for (int ks = 0; ks < 2; ++ks)
    kf[ks] = *reinterpret_cast<const bf16x8*>(
        &kb[base + (size_t)(t0 + w * 16 + l15) * HD_ + ks * 32 + lh * 8]);

  f32x4 o[4];
#pragma unroll
  for (int i = 0; i < 4; ++i) o[i] = {0.f, 0.f, 0.f, 0.f};
  float mrun[4], lrun[4];
#pragma unroll
  for (int r = 0; r < 4; ++r) { mrun[r] = -1e30f; lrun[r] = 0.f; }

  for (int j = 0; j <= jt; ++j) {
    const int s0 = j * 64;
    __syncthreads();
    // stage q tile row-major
#pragma unroll
    for (int i = 0; i < 2; ++i) {
      int c = i * 256 + tid;
      int row = c >> 3, c8 = c & 7;
      bf16x8 qv = *reinterpret_cast<const bf16x8*>(&qb[base + (size_t)(s0 + row) * HD_ + c8 * 8]);
      *reinterpret_cast<bf16x8*>(&q_lds[row * 72 + c8 * 8]) = qv;
    }
    // stage v transposed: chunk -> s = c&63, d0 = (c>>6)*8 (conflict-free LDS writes)
#pragma unroll
    for (int i = 0; i < 2; ++i) {
      int c = i * 256 + tid;
      int ss = c & 63, d0 = (c >> 6) * 8;
      bf16x8 vv = *reinterpret_cast<const bf16x8*>(&vb[base + (size_t)(s0 + ss) * HD_ + d0]);
#pragma unroll
      for (int jj = 0; jj < 8; ++jj) v_lds[(d0 + jj) * 72 + ss] = (unsigned short)vv[jj];
    }
    __syncthreads();

    // S = K * Q^T  (16x64 per wave)
    f32x4 sf[4];
#pragma unroll
    for (int cf = 0; cf < 4; ++cf) sf[cf] = {0.f, 0.f, 0.f, 0.f};
#pragma unroll
    for (int ks = 0; ks < 2; ++ks) {
#pragma unroll
      for (int cf = 0; cf < 4; ++cf) {
        bf16x8 bq = *reinterpret_cast<const bf16x8*>(&q_lds[(cf * 16 + l15) * 72 + ks * 32 + lh * 8]);
        sf[cf] = __builtin_amdgcn_mfma_f32_16x16x32_bf16(kf[ks], bq, sf[cf], 0, 0, 0);
      }
    }

    const bool diag = (j == jt);
    float pv[4][4];
#pragma unroll
    for (int r = 0; r < 4; ++r) {
      const int tg = t0 + w * 16 + lh * 4 + r;
      float pm = -1e30f;
#pragma unroll
      for (int cf = 0; cf < 4; ++cf) {
        float v = sf[cf][r] * 0.03125f;   // 1/sqrt(1024)
        if (diag && (s0 + cf * 16 + l15) > tg) v = -1e30f;
        pv[cf][r] = v;
        pm = fmaxf(pm, v);
      }
      pm = fmaxf(pm, __shfl_xor(pm, 1));
      pm = fmaxf(pm, __shfl_xor(pm, 2));
      pm = fmaxf(pm, __shfl_xor(pm, 4));
      pm = fmaxf(pm, __shfl_xor(pm, 8));
      float mn = fmaxf(mrun[r], pm);
      float scl = __expf(mrun[r] - mn);
      mrun[r] = mn;
      float rs = 0.f;
#pragma unroll
      for (int cf = 0; cf < 4; ++cf) {
        float e = __expf(pv[cf][r] - mn);
        pv[cf][r] = e;
        rs += e;
      }
      rs += __shfl_xor(rs, 1);
      rs += __shfl_xor(rs, 2);
      rs += __shfl_xor(rs, 4);
      rs += __shfl_xor(rs, 8);
      lrun[r] = lrun[r] * scl + rs;
#pragma unroll
      for (int df = 0; df < 4; ++df) o[df][r] *= scl;
    }
    // P -> LDS (bf16)
#pragma unroll
    for (int cf = 0; cf < 4; ++cf)
#pragma unroll
      for (int r = 0; r < 4; ++r)
        p_lds[(w * 16 + lh * 4 + r) * 72 + cf * 16 + l15] = f2bf(pv[cf][r]);
    __syncthreads();

    // O += P * V
#pragma unroll
    for (int ks = 0; ks < 2; ++ks) {
      bf16x8 pa = *reinterpret_cast<const bf16x8*>(&p_lds[(w * 16 + l15) * 72 + ks * 32 + lh * 8]);
#pragma unroll
      for (int df = 0; df < 4; ++df) {
        bf16x8 bv = *reinterpret_cast<const bf16x8*>(&v_lds[(df * 16 + l15) * 72 + ks * 32 + lh * 8]);
        o[df] = __builtin_amdgcn_mfma_f32_16x16x32_bf16(pa, bv, o[df], 0, 0, 0);
      }
    }
  }

  // normalize + store fp32
#pragma unroll
  for (int r = 0; r < 4; ++r) {
    float inv = 1.f / lrun[r];
    int row = t0 + w * 16 + lh * 4 + r;
#pragma unroll
    for (int df = 0; df < 4; ++df)
      out[base + (size_t)row * HD_ + df * 16 + l15] = o[df][r] * inv;
  }
}

extern "C" void kernel_launch(void* const* d_in, const int* in_sizes, int n_in,
                              void* d_out, int out_size, void* d_ws, size_t ws_size,
                              hipStream_t stream) {
  const float* x  = (const float*)d_in[0];
  const float* Wk = (const float*)d_in[1];
  const float* Wq = (const float*)d_in[2];
  const float* Wv = (const float*)d_in[3];
  float* out = (float*)d_out;

  char* ws = (char*)d_ws;
  unsigned short* wt = (unsigned short*)ws;                                  // 384 KB
  unsigned short* kb = (unsigned short*)(ws + 524288);                       // 4 MB
  unsigned short* qb = (unsigned short*)(ws + 524288 + 4 * 1024 * 1024);     // 4 MB
  unsigned short* vb = (unsigned short*)(ws + 524288 + 8 * 1024 * 1024);     // 4 MB

  hipLaunchKernelGGL(wconv_kernel, dim3(768), dim3(256), 0, stream, Wk, Wq, Wv, wt);
  hipLaunchKernelGGL(qkv_kernel, dim3(256), dim3(512), 0, stream, x, wt, kb, qb, vb);
  hipLaunchKernelGGL(attn_kernel, dim3(32, 16), dim3(256), 0, stream, kb, qb, vb, out);
}

// Round 2
// 99.563 us; speedup vs baseline: 1.4275x; 1.4275x over previous
//
#include <hip/hip_runtime.h>
#include <hip/hip_bf16.h>

#define B_ 16
#define T_ 2048
#define C_ 1024
#define HD_ 64

typedef __attribute__((ext_vector_type(8))) short bf16x8;
typedef __attribute__((ext_vector_type(4))) float f32x4;

__device__ __forceinline__ unsigned short f2bf(float f) {
  unsigned int u = __builtin_bit_cast(unsigned int, f);
  unsigned int r = (u + 0x7fffu + ((u >> 16) & 1u)) >> 16;
  return (unsigned short)r;
}

__device__ __forceinline__ bf16x8 cvt8(float4 a, float4 b) {
  bf16x8 r;
  r[0] = (short)f2bf(a.x); r[1] = (short)f2bf(a.y);
  r[2] = (short)f2bf(a.z); r[3] = (short)f2bf(a.w);
  r[4] = (short)f2bf(b.x); r[5] = (short)f2bf(b.y);
  r[6] = (short)f2bf(b.z); r[7] = (short)f2bf(b.w);
  return r;
}

// ---------------- W convert + transpose: wt[m][d][c] = bf16(W_m[c][d]) ----------------
__global__ void wconv_kernel(const float* __restrict__ Wk, const float* __restrict__ Wq,
                             const float* __restrict__ Wv, unsigned short* __restrict__ wt) {
  int o = blockIdx.x * 256 + threadIdx.x;   // 3*64*1024 = 196608 total
  if (o >= 3 * HD_ * C_) return;
  int m = o >> 16;
  int d = (o >> 10) & 63;
  int c = o & 1023;
  const float* W = (m == 0) ? Wk : (m == 1) ? Wq : Wv;
  wt[o] = f2bf(W[c * HD_ + d]);
}

// ---------------- QKV projection v2 ----------------
// 512 blocks x 256 threads (4 waves). 64 rows/block, 16 rows/wave.
// x: global -> reg directly (read exactly once), software-pipelined 1 iter ahead.
// W: bf16 tile [192][32] per K-step, double-buffered LDS via global_load_lds,
//    XOR chunk-swizzle on global source so ds_read_b128 frags are conflict-free.
__global__ __launch_bounds__(256, 5) void qkv_kernel(const float* __restrict__ x,
                                                     const unsigned short* __restrict__ wt,
                                                     unsigned short* __restrict__ kb,
                                                     unsigned short* __restrict__ qb,
                                                     unsigned short* __restrict__ vb) {
  __shared__ __align__(16) unsigned short wl[2 * 6144];   // 2 x 12288 B

  const int tid = threadIdx.x;
  const int lane = tid & 63;
  const int w = tid >> 6;
  const int l15 = lane & 15;
  const int lh = lane >> 4;
  const int r0 = blockIdx.x * 64;

  // frag-read base: row d = cf*16 + l15, chunk lh, swizzled chunk = lh ^ ((l15>>1)&3)
  const int rb = l15 * 32 + ((lh ^ ((l15 >> 1) & 3)) << 3);   // ushort offset

  const float* xp = x + (size_t)(r0 + w * 16 + l15) * C_ + lh * 8;

  f32x4 acc[12];
#pragma unroll
  for (int i = 0; i < 12; ++i) acc[i] = {0.f, 0.f, 0.f, 0.f};

#define STAGE_W(buf, kk)                                                              \
  do {                                                                                \
    _Pragma("unroll")                                                                 \
    for (int i_ = 0; i_ < 3; ++i_) {                                                  \
      const int L_ = (w * 3 + i_) << 10;          /* wave-uniform byte base */        \
      const int d_ = (L_ >> 6) + (lane >> 2);                                         \
      const int kc_ = lane & 3;                                                       \
      const int sw_ = (d_ >> 1) & 3;                                                  \
      const unsigned short* g_ = wt + ((size_t)d_ << 10) + (kk) * 32 + ((kc_ ^ sw_) << 3); \
      __builtin_amdgcn_global_load_lds(                                               \
          (const __attribute__((address_space(1))) void*)g_,                          \
          (__attribute__((address_space(3))) void*)&wl[(buf) * 6144 + (L_ >> 1)],     \
          16, 0, 0);                                                                  \
    }                                                                                 \
  } while (0)

  STAGE_W(0, 0);
  float4 f0 = *reinterpret_cast<const float4*>(xp);
  float4 f1 = *reinterpret_cast<const float4*>(xp + 4);
  __syncthreads();

  for (int kk = 0; kk < 32; ++kk) {
    const int cur = kk & 1;
    if (kk < 31) STAGE_W(cur ^ 1, kk + 1);
    const int koff = (kk < 31) ? (kk + 1) * 32 : kk * 32;
    float4 n0 = *reinterpret_cast<const float4*>(xp + koff);
    float4 n1 = *reinterpret_cast<const float4*>(xp + koff + 4);

    bf16x8 a = cvt8(f0, f1);
    const unsigned short* wbase = &wl[cur * 6144 + rb];
#pragma unroll
    for (int cf = 0; cf < 12; ++cf) {
      bf16x8 bfrag = *reinterpret_cast<const bf16x8*>(wbase + cf * 512);
      acc[cf] = __builtin_amdgcn_mfma_f32_16x16x32_bf16(a, bfrag, acc[cf], 0, 0, 0);
    }
    __syncthreads();
    f0 = n0; f1 = n1;
  }
#undef STAGE_W

  // epilogue: C/D layout col=lane&15, row=(lane>>4)*4+r. Fold 1/sqrt(C)=2^-5 into k.
#pragma unroll
  for (int cf = 0; cf < 4; ++cf) {
    int col = cf * 16 + l15;
#pragma unroll
    for (int r = 0; r < 4; ++r) {
      size_t row = (size_t)(r0 + w * 16 + lh * 4 + r);
      kb[row * HD_ + col] = f2bf(acc[cf][r] * 0.03125f);
      qb[row * HD_ + col] = f2bf(acc[4 + cf][r]);
      vb[row * HD_ + col] = f2bf(acc[8 + cf][r]);
    }
  }
}

// ---------------- flash attention (queries = k rows, keys = q rows) ----------------
__global__ __launch_bounds__(256) void attn_kernel(const unsigned short* __restrict__ kb,
                                                   const unsigned short* __restrict__ qb,
                                                   const unsigned short* __restrict__ vb,
                                                   float* __restrict__ out) {
  __shared__ __align__(16) unsigned short q_lds[64 * 72];  // [s][d] padded
  __shared__ __align__(16) unsigned short v_lds[64 * 72];  // [d][s] padded (transposed)
  __shared__ __align__(16) unsigned short p_lds[64 * 72];  // [t][s] padded

  const int tid = threadIdx.x;
  const int lane = tid & 63;
  const int w = tid >> 6;          // 4 waves x 16 query rows
  const int bid = blockIdx.x;      // heavy tiles first
  const int jt = 31 - (bid >> 4);
  const int b = bid & 15;
  const int t0 = jt * 64;
  const int l15 = lane & 15;
  const int lh = lane >> 4;
  const size_t base = (size_t)b * T_ * HD_;

  // hoist k fragments (A operand; already scaled by 1/32 in qkv), 2 d-halves
  bf16x8 kf[2];
#pragma unroll
  for (int ks = 0; ks < 2; ++ks)
    kf[ks] = *reinterpret_cast<const bf16x8*>(
        &kb[base + (size_t)(t0 + w * 16 + l15) * HD_ + ks * 32 + lh * 8]);

  f32x4 o[4];
#pragma unroll
  for (int i = 0; i < 4; ++i) o[i] = {0.f, 0.f, 0.f, 0.f};
  float mrun[4], lrun[4];
#pragma unroll
  for (int r = 0; r < 4; ++r) { mrun[r] = -1e30f; lrun[r] = 0.f; }

  for (int j = 0; j <= jt; ++j) {
    const int s0 = j * 64;
    __syncthreads();
#pragma unroll
    for (int i = 0; i < 2; ++i) {
      int c = i * 256 + tid;
      int row = c >> 3, c8 = c & 7;
      bf16x8 qv = *reinterpret_cast<const bf16x8*>(&qb[base + (size_t)(s0 + row) * HD_ + c8 * 8]);
      *reinterpret_cast<bf16x8*>(&q_lds[row * 72 + c8 * 8]) = qv;
    }
#pragma unroll
    for (int i = 0; i < 2; ++i) {
      int c = i * 256 + tid;
      int ss = c & 63, d0 = (c >> 6) * 8;
      bf16x8 vv = *reinterpret_cast<const bf16x8*>(&vb[base + (size_t)(s0 + ss) * HD_ + d0]);
#pragma unroll
      for (int jj = 0; jj < 8; ++jj) v_lds[(d0 + jj) * 72 + ss] = (unsigned short)vv[jj];
    }
    __syncthreads();

    // S = K * Q^T  (16x64 per wave)
    f32x4 sf[4];
#pragma unroll
    for (int cf = 0; cf < 4; ++cf) sf[cf] = {0.f, 0.f, 0.f, 0.f};
#pragma unroll
    for (int ks = 0; ks < 2; ++ks) {
#pragma unroll
      for (int cf = 0; cf < 4; ++cf) {
        bf16x8 bq = *reinterpret_cast<const bf16x8*>(&q_lds[(cf * 16 + l15) * 72 + ks * 32 + lh * 8]);
        sf[cf] = __builtin_amdgcn_mfma_f32_16x16x32_bf16(kf[ks], bq, sf[cf], 0, 0, 0);
      }
    }

    const bool diag = (j == jt);
    float pv[4][4];
#pragma unroll
    for (int r = 0; r < 4; ++r) {
      const int tg = t0 + w * 16 + lh * 4 + r;
      float pm = -1e30f;
#pragma unroll
      for (int cf = 0; cf < 4; ++cf) {
        float v = sf[cf][r];   // scale pre-folded into kb
        if (diag && (s0 + cf * 16 + l15) > tg) v = -1e30f;
        pv[cf][r] = v;
        pm = fmaxf(pm, v);
      }
      pm = fmaxf(pm, __shfl_xor(pm, 1));
      pm = fmaxf(pm, __shfl_xor(pm, 2));
      pm = fmaxf(pm, __shfl_xor(pm, 4));
      pm = fmaxf(pm, __shfl_xor(pm, 8));
      float mn = fmaxf(mrun[r], pm);
      float scl = __expf(mrun[r] - mn);
      mrun[r] = mn;
      float rs = 0.f;
#pragma unroll
      for (int cf = 0; cf < 4; ++cf) {
        float e = __expf(pv[cf][r] - mn);
        pv[cf][r] = e;
        rs += e;
      }
      rs += __shfl_xor(rs, 1);
      rs += __shfl_xor(rs, 2);
      rs += __shfl_xor(rs, 4);
      rs += __shfl_xor(rs, 8);
      lrun[r] = lrun[r] * scl + rs;
#pragma unroll
      for (int df = 0; df < 4; ++df) o[df][r] *= scl;
    }
#pragma unroll
    for (int cf = 0; cf < 4; ++cf)
#pragma unroll
      for (int r = 0; r < 4; ++r)
        p_lds[(w * 16 + lh * 4 + r) * 72 + cf * 16 + l15] = f2bf(pv[cf][r]);
    __syncthreads();

#pragma unroll
    for (int ks = 0; ks < 2; ++ks) {
      bf16x8 pa = *reinterpret_cast<const bf16x8*>(&p_lds[(w * 16 + l15) * 72 + ks * 32 + lh * 8]);
#pragma unroll
      for (int df = 0; df < 4; ++df) {
        bf16x8 bv = *reinterpret_cast<const bf16x8*>(&v_lds[(df * 16 + l15) * 72 + ks * 32 + lh * 8]);
        o[df] = __builtin_amdgcn_mfma_f32_16x16x32_bf16(pa, bv, o[df], 0, 0, 0);
      }
    }
  }

#pragma unroll
  for (int r = 0; r < 4; ++r) {
    float inv = 1.f / lrun[r];
    int row = t0 + w * 16 + lh * 4 + r;
#pragma unroll
    for (int df = 0; df < 4; ++df)
      out[base + (size_t)row * HD_ + df * 16 + l15] = o[df][r] * inv;
  }
}

extern "C" void kernel_launch(void* const* d_in, const int* in_sizes, int n_in,
                              void* d_out, int out_size, void* d_ws, size_t ws_size,
                              hipStream_t stream) {
  const float* x  = (const float*)d_in[0];
  const float* Wk = (const float*)d_in[1];
  const float* Wq = (const float*)d_in[2];
  const float* Wv = (const float*)d_in[3];
  float* out = (float*)d_out;

  char* ws = (char*)d_ws;
  unsigned short* wt = (unsigned short*)ws;                                  // 384 KB
  unsigned short* kb = (unsigned short*)(ws + 524288);                       // 4 MB
  unsigned short* qb = (unsigned short*)(ws + 524288 + 4 * 1024 * 1024);     // 4 MB
  unsigned short* vb = (unsigned short*)(ws + 524288 + 8 * 1024 * 1024);     // 4 MB

  hipLaunchKernelGGL(wconv_kernel, dim3(768), dim3(256), 0, stream, Wk, Wq, Wv, wt);
  hipLaunchKernelGGL(qkv_kernel, dim3(512), dim3(256), 0, stream, x, wt, kb, qb, vb);
  hipLaunchKernelGGL(attn_kernel, dim3(512), dim3(256), 0, stream, kb, qb, vb, out);
}

// Round 3
// 94.176 us; speedup vs baseline: 1.5091x; 1.0572x over previous
//
#include <hip/hip_runtime.h>
#include <hip/hip_bf16.h>

#define B_ 16
#define T_ 2048
#define C_ 1024
#define HD_ 64

typedef __attribute__((ext_vector_type(8))) short bf16x8;
typedef __attribute__((ext_vector_type(4))) float f32x4;

__device__ __forceinline__ unsigned short f2bf(float f) {
  return __builtin_bit_cast(unsigned short, __float2bfloat16(f));
}

__device__ __forceinline__ bf16x8 cvt8(float4 a, float4 b) {
  bf16x8 r;
  r[0] = (short)f2bf(a.x); r[1] = (short)f2bf(a.y);
  r[2] = (short)f2bf(a.z); r[3] = (short)f2bf(a.w);
  r[4] = (short)f2bf(b.x); r[5] = (short)f2bf(b.y);
  r[6] = (short)f2bf(b.z); r[7] = (short)f2bf(b.w);
  return r;
}

// ---- W convert + transpose + XOR-swizzle: wt2[r][c] , r = m*64+d (192 rows x 1024 K) ----
// physical 8-elem slot s of row r holds logical slot (s&~7) | ((s^r)&7).
// 1/sqrt(C) = 2^-5 folded into Wk (m==0).
__global__ void wconv_kernel(const float* __restrict__ Wk, const float* __restrict__ Wq,
                             const float* __restrict__ Wv, unsigned short* __restrict__ wt2) {
  int o = blockIdx.x * 256 + threadIdx.x;   // 3*64*1024 = 196608 total
  if (o >= 3 * HD_ * C_) return;
  int r = o >> 10;          // 0..191
  int c = o & 1023;
  int s = c >> 3, e = c & 7;
  int lc = (((s & 0x78) | ((s ^ r) & 7)) << 3) | e;   // logical K index
  int m = r >> 6, d = r & 63;
  const float* W = (m == 0) ? Wk : (m == 1) ? Wq : Wv;
  float v = W[lc * HD_ + d];
  if (m == 0) v *= 0.03125f;
  wt2[o] = f2bf(v);
}

// ---------------- QKV projection v3: counted-vmcnt pipeline ----------------
// 512 blocks x 256 threads (4 waves), 64 rows/block, 16 rows/wave, BK=64 (16 K-steps).
// W: 24 KB tile double-buffered LDS via global_load_lds (pre-swizzled source).
// x: global->reg, depth-2 prefetch, triple-buffered regs (static indices).
// Raw s_barrier + s_waitcnt vmcnt(14): next iter's loads stay in flight.
__global__ __launch_bounds__(256, 2) void qkv_kernel(const float* __restrict__ x,
                                                     const unsigned short* __restrict__ wt2,
                                                     unsigned short* __restrict__ kb,
                                                     unsigned short* __restrict__ qb,
                                                     unsigned short* __restrict__ vb) {
  __shared__ __align__(16) unsigned short wl[2 * 12288];   // 2 x 24576 B

  const int tid = threadIdx.x;
  const int lane = tid & 63;
  const int w = tid >> 6;
  const int l15 = lane & 15;
  const int lh = lane >> 4;
  const int r0 = blockIdx.x * 64;
  const int sw = l15 & 7;
  const int c0 = (lh ^ sw) * 8;          // phys chunk (ushort) for ks=0
  const int c1 = ((4 | lh) ^ sw) * 8;    // ks=1

  const float* xp = x + (size_t)(r0 + w * 16 + l15) * C_ + lh * 8;

  f32x4 acc[12];
#pragma unroll
  for (int i = 0; i < 12; ++i) acc[i] = {0.f, 0.f, 0.f, 0.f};

  float4 xr0[4], xr1[4], xr2[4];

#define STAGE(BUF, KK)                                                               \
  do {                                                                               \
    _Pragma("unroll")                                                                \
    for (int i_ = 0; i_ < 6; ++i_) {                                                 \
      const int gp_ = w * 6 + i_;                                                    \
      const int row_ = gp_ * 8 + (lane >> 3);                                        \
      const unsigned short* g_ = wt2 + row_ * 1024 + (KK) * 64 + (lane & 7) * 8;     \
      __builtin_amdgcn_global_load_lds(                                              \
          (const __attribute__((address_space(1))) void*)g_,                         \
          (__attribute__((address_space(3))) void*)&wl[(BUF) * 12288 + gp_ * 512],   \
          16, 0, 0);                                                                 \
    }                                                                                \
  } while (0)

#define XLOAD(XR, KK)                               \
  do {                                              \
    const float* p_ = xp + (KK) * 64;               \
    XR[0] = *(const float4*)(p_);                   \
    XR[1] = *(const float4*)(p_ + 4);               \
    XR[2] = *(const float4*)(p_ + 32);              \
    XR[3] = *(const float4*)(p_ + 36);              \
  } while (0)

#define COMPUTE(K, XR)                                                                   \
  do {                                                                                   \
    const unsigned short* wb = &wl[((K) & 1) * 12288];                                   \
    bf16x8 a0 = cvt8(XR[0], XR[1]);                                                      \
    bf16x8 a1 = cvt8(XR[2], XR[3]);                                                      \
    _Pragma("unroll")                                                                    \
    for (int cf = 0; cf < 12; ++cf) {                                                    \
      bf16x8 b0 = *(const bf16x8*)&wb[((cf >> 2) * 64 + (cf & 3) * 16 + l15) * 64 + c0]; \
      acc[cf] = __builtin_amdgcn_mfma_f32_16x16x32_bf16(a0, b0, acc[cf], 0, 0, 0);       \
    }                                                                                    \
    _Pragma("unroll")                                                                    \
    for (int cf = 0; cf < 12; ++cf) {                                                    \
      bf16x8 b1 = *(const bf16x8*)&wb[((cf >> 2) * 64 + (cf & 3) * 16 + l15) * 64 + c1]; \
      acc[cf] = __builtin_amdgcn_mfma_f32_16x16x32_bf16(a1, b1, acc[cf], 0, 0, 0);       \
    }                                                                                    \
  } while (0)

#define SB __builtin_amdgcn_sched_barrier(0)

#define ITER(K, XCUR, XPRE, VM)                                    \
  do {                                                             \
    if ((K) < 15) STAGE(((K) + 1) & 1, (K) + 1);                   \
    SB;                                                            \
    if ((K) < 14) XLOAD(XPRE, (K) + 2);                            \
    SB;                                                            \
    asm volatile("s_waitcnt vmcnt(" #VM ")" ::: "memory");         \
    SB;                                                            \
    __builtin_amdgcn_s_barrier();                                  \
    COMPUTE(K, XCUR);                                              \
    __builtin_amdgcn_s_barrier();                                  \
  } while (0)

  // prologue: stage(0), x(0), x(1)
  STAGE(0, 0);
  SB;
  XLOAD(xr0, 0);
  XLOAD(xr1, 1);
  SB;

  ITER(0, xr0, xr2, 14);
  ITER(1, xr1, xr0, 14);
  ITER(2, xr2, xr1, 14);
  ITER(3, xr0, xr2, 14);
  ITER(4, xr1, xr0, 14);
  ITER(5, xr2, xr1, 14);
  ITER(6, xr0, xr2, 14);
  ITER(7, xr1, xr0, 14);
  ITER(8, xr2, xr1, 14);
  ITER(9, xr0, xr2, 14);
  ITER(10, xr1, xr0, 14);
  ITER(11, xr2, xr1, 14);
  ITER(12, xr0, xr2, 14);
  ITER(13, xr1, xr0, 14);
  ITER(14, xr2, xr1, 10);
  ITER(15, xr0, xr2, 0);

#undef ITER
#undef COMPUTE
#undef XLOAD
#undef STAGE
#undef SB

  // epilogue: C/D layout col=lane&15, row=(lane>>4)*4+r (scale pre-folded in wconv)
#pragma unroll
  for (int cf = 0; cf < 4; ++cf) {
    int col = cf * 16 + l15;
#pragma unroll
    for (int r = 0; r < 4; ++r) {
      size_t row = (size_t)(r0 + w * 16 + lh * 4 + r);
      kb[row * HD_ + col] = f2bf(acc[cf][r]);
      qb[row * HD_ + col] = f2bf(acc[4 + cf][r]);
      vb[row * HD_ + col] = f2bf(acc[8 + cf][r]);
    }
  }
}

// ---------------- flash attention (queries = k rows, keys = q rows) ----------------
__global__ __launch_bounds__(256) void attn_kernel(const unsigned short* __restrict__ kb,
                                                   const unsigned short* __restrict__ qb,
                                                   const unsigned short* __restrict__ vb,
                                                   float* __restrict__ out) {
  __shared__ __align__(16) unsigned short q_lds[64 * 72];  // [s][d] padded
  __shared__ __align__(16) unsigned short v_lds[64 * 72];  // [d][s] padded (transposed)
  __shared__ __align__(16) unsigned short p_lds[64 * 72];  // [t][s] padded

  const int tid = threadIdx.x;
  const int lane = tid & 63;
  const int w = tid >> 6;          // 4 waves x 16 query rows
  const int bid = blockIdx.x;      // heavy tiles first
  const int jt = 31 - (bid >> 4);
  const int b = bid & 15;
  const int t0 = jt * 64;
  const int l15 = lane & 15;
  const int lh = lane >> 4;
  const size_t base = (size_t)b * T_ * HD_;

  bf16x8 kf[2];
#pragma unroll
  for (int ks = 0; ks < 2; ++ks)
    kf[ks] = *reinterpret_cast<const bf16x8*>(
        &kb[base + (size_t)(t0 + w * 16 + l15) * HD_ + ks * 32 + lh * 8]);

  f32x4 o[4];
#pragma unroll
  for (int i = 0; i < 4; ++i) o[i] = {0.f, 0.f, 0.f, 0.f};
  float mrun[4], lrun[4];
#pragma unroll
  for (int r = 0; r < 4; ++r) { mrun[r] = -1e30f; lrun[r] = 0.f; }

  for (int j = 0; j <= jt; ++j) {
    const int s0 = j * 64;
    __syncthreads();
#pragma unroll
    for (int i = 0; i < 2; ++i) {
      int c = i * 256 + tid;
      int row = c >> 3, c8 = c & 7;
      bf16x8 qv = *reinterpret_cast<const bf16x8*>(&qb[base + (size_t)(s0 + row) * HD_ + c8 * 8]);
      *reinterpret_cast<bf16x8*>(&q_lds[row * 72 + c8 * 8]) = qv;
    }
#pragma unroll
    for (int i = 0; i < 2; ++i) {
      int c = i * 256 + tid;
      int ss = c & 63, d0 = (c >> 6) * 8;
      bf16x8 vv = *reinterpret_cast<const bf16x8*>(&vb[base + (size_t)(s0 + ss) * HD_ + d0]);
#pragma unroll
      for (int jj = 0; jj < 8; ++jj) v_lds[(d0 + jj) * 72 + ss] = (unsigned short)vv[jj];
    }
    __syncthreads();

    f32x4 sf[4];
#pragma unroll
    for (int cf = 0; cf < 4; ++cf) sf[cf] = {0.f, 0.f, 0.f, 0.f};
#pragma unroll
    for (int ks = 0; ks < 2; ++ks) {
#pragma unroll
      for (int cf = 0; cf < 4; ++cf) {
        bf16x8 bq = *reinterpret_cast<const bf16x8*>(&q_lds[(cf * 16 + l15) * 72 + ks * 32 + lh * 8]);
        sf[cf] = __builtin_amdgcn_mfma_f32_16x16x32_bf16(kf[ks], bq, sf[cf], 0, 0, 0);
      }
    }

    const bool diag = (j == jt);
    float pv[4][4];
#pragma unroll
    for (int r = 0; r < 4; ++r) {
      const int tg = t0 + w * 16 + lh * 4 + r;
      float pm = -1e30f;
#pragma unroll
      for (int cf = 0; cf < 4; ++cf) {
        float v = sf[cf][r];
        if (diag && (s0 + cf * 16 + l15) > tg) v = -1e30f;
        pv[cf][r] = v;
        pm = fmaxf(pm, v);
      }
      pm = fmaxf(pm, __shfl_xor(pm, 1));
      pm = fmaxf(pm, __shfl_xor(pm, 2));
      pm = fmaxf(pm, __shfl_xor(pm, 4));
      pm = fmaxf(pm, __shfl_xor(pm, 8));
      float mn = fmaxf(mrun[r], pm);
      float scl = __expf(mrun[r] - mn);
      mrun[r] = mn;
      float rs = 0.f;
#pragma unroll
      for (int cf = 0; cf < 4; ++cf) {
        float e = __expf(pv[cf][r] - mn);
        pv[cf][r] = e;
        rs += e;
      }
      rs += __shfl_xor(rs, 1);
      rs += __shfl_xor(rs, 2);
      rs += __shfl_xor(rs, 4);
      rs += __shfl_xor(rs, 8);
      lrun[r] = lrun[r] * scl + rs;
#pragma unroll
      for (int df = 0; df < 4; ++df) o[df][r] *= scl;
    }
#pragma unroll
    for (int cf = 0; cf < 4; ++cf)
#pragma unroll
      for (int r = 0; r < 4; ++r)
        p_lds[(w * 16 + lh * 4 + r) * 72 + cf * 16 + l15] = f2bf(pv[cf][r]);
    __syncthreads();

#pragma unroll
    for (int ks = 0; ks < 2; ++ks) {
      bf16x8 pa = *reinterpret_cast<const bf16x8*>(&p_lds[(w * 16 + l15) * 72 + ks * 32 + lh * 8]);
#pragma unroll
      for (int df = 0; df < 4; ++df) {
        bf16x8 bv = *reinterpret_cast<const bf16x8*>(&v_lds[(df * 16 + l15) * 72 + ks * 32 + lh * 8]);
        o[df] = __builtin_amdgcn_mfma_f32_16x16x32_bf16(pa, bv, o[df], 0, 0, 0);
      }
    }
  }

#pragma unroll
  for (int r = 0; r < 4; ++r) {
    float inv = 1.f / lrun[r];
    int row = t0 + w * 16 + lh * 4 + r;
#pragma unroll
    for (int df = 0; df < 4; ++df)
      out[base + (size_t)row * HD_ + df * 16 + l15] = o[df][r] * inv;
  }
}

extern "C" void kernel_launch(void* const* d_in, const int* in_sizes, int n_in,
                              void* d_out, int out_size, void* d_ws, size_t ws_size,
                              hipStream_t stream) {
  const float* x  = (const float*)d_in[0];
  const float* Wk = (const float*)d_in[1];
  const float* Wq = (const float*)d_in[2];
  const float* Wv = (const float*)d_in[3];
  float* out = (float*)d_out;

  char* ws = (char*)d_ws;
  unsigned short* wt2 = (unsigned short*)ws;                                 // 384 KB
  unsigned short* kb = (unsigned short*)(ws + 524288);                       // 4 MB
  unsigned short* qb = (unsigned short*)(ws + 524288 + 4 * 1024 * 1024);     // 4 MB
  unsigned short* vb = (unsigned short*)(ws + 524288 + 8 * 1024 * 1024);     // 4 MB

  hipLaunchKernelGGL(wconv_kernel, dim3(768), dim3(256), 0, stream, Wk, Wq, Wv, wt2);
  hipLaunchKernelGGL(qkv_kernel, dim3(512), dim3(256), 0, stream, x, wt2, kb, qb, vb);
  hipLaunchKernelGGL(attn_kernel, dim3(512), dim3(256), 0, stream, kb, qb, vb, out);
}

// Round 4
// 90.149 us; speedup vs baseline: 1.5765x; 1.0447x over previous
//
#include <hip/hip_runtime.h>
#include <hip/hip_bf16.h>

#define B_ 16
#define T_ 2048
#define C_ 1024
#define HD_ 64

typedef __attribute__((ext_vector_type(8))) short bf16x8;
typedef __attribute__((ext_vector_type(4))) float f32x4;

__device__ __forceinline__ unsigned short f2bf(float f) {
  return __builtin_bit_cast(unsigned short, __float2bfloat16(f));
}

__device__ __forceinline__ bf16x8 cvt8(float4 a, float4 b) {
  bf16x8 r;
  r[0] = (short)f2bf(a.x); r[1] = (short)f2bf(a.y);
  r[2] = (short)f2bf(a.z); r[3] = (short)f2bf(a.w);
  r[4] = (short)f2bf(b.x); r[5] = (short)f2bf(b.y);
  r[6] = (short)f2bf(b.z); r[7] = (short)f2bf(b.w);
  return r;
}

// ---- W convert + transpose + XOR-swizzle: wt2[r][c] , r = m*64+d (192 rows x 1024 K) ----
// physical 8-elem slot s of row r holds logical slot (s&~7) | ((s^r)&7).
// 1/sqrt(C) = 2^-5 AND log2(e) folded into Wk (scores then live in exp2 domain).
__global__ void wconv_kernel(const float* __restrict__ Wk, const float* __restrict__ Wq,
                             const float* __restrict__ Wv, unsigned short* __restrict__ wt2) {
  int o = blockIdx.x * 256 + threadIdx.x;   // 3*64*1024 = 196608 total
  if (o >= 3 * HD_ * C_) return;
  int r = o >> 10;          // 0..191
  int c = o & 1023;
  int s = c >> 3, e = c & 7;
  int lc = (((s & 0x78) | ((s ^ r) & 7)) << 3) | e;   // logical K index
  int m = r >> 6, d = r & 63;
  const float* W = (m == 0) ? Wk : (m == 1) ? Wq : Wv;
  float v = W[lc * HD_ + d];
  if (m == 0) v *= 0.03125f * 1.44269504088896f;
  wt2[o] = f2bf(v);
}

// ---------------- QKV projection v3 (unchanged from round 3) ----------------
__global__ __launch_bounds__(256, 2) void qkv_kernel(const float* __restrict__ x,
                                                     const unsigned short* __restrict__ wt2,
                                                     unsigned short* __restrict__ kb,
                                                     unsigned short* __restrict__ qb,
                                                     unsigned short* __restrict__ vb) {
  __shared__ __align__(16) unsigned short wl[2 * 12288];   // 2 x 24576 B

  const int tid = threadIdx.x;
  const int lane = tid & 63;
  const int w = tid >> 6;
  const int l15 = lane & 15;
  const int lh = lane >> 4;
  const int r0 = blockIdx.x * 64;
  const int sw = l15 & 7;
  const int c0 = (lh ^ sw) * 8;          // phys chunk (ushort) for ks=0
  const int c1 = ((4 | lh) ^ sw) * 8;    // ks=1

  const float* xp = x + (size_t)(r0 + w * 16 + l15) * C_ + lh * 8;

  f32x4 acc[12];
#pragma unroll
  for (int i = 0; i < 12; ++i) acc[i] = {0.f, 0.f, 0.f, 0.f};

  float4 xr0[4], xr1[4], xr2[4];

#define STAGE(BUF, KK)                                                               \
  do {                                                                               \
    _Pragma("unroll")                                                                \
    for (int i_ = 0; i_ < 6; ++i_) {                                                 \
      const int gp_ = w * 6 + i_;                                                    \
      const int row_ = gp_ * 8 + (lane >> 3);                                        \
      const unsigned short* g_ = wt2 + row_ * 1024 + (KK) * 64 + (lane & 7) * 8;     \
      __builtin_amdgcn_global_load_lds(                                              \
          (const __attribute__((address_space(1))) void*)g_,                         \
          (__attribute__((address_space(3))) void*)&wl[(BUF) * 12288 + gp_ * 512],   \
          16, 0, 0);                                                                 \
    }                                                                                \
  } while (0)

#define XLOAD(XR, KK)                               \
  do {                                              \
    const float* p_ = xp + (KK) * 64;               \
    XR[0] = *(const float4*)(p_);                   \
    XR[1] = *(const float4*)(p_ + 4);               \
    XR[2] = *(const float4*)(p_ + 32);              \
    XR[3] = *(const float4*)(p_ + 36);              \
  } while (0)

#define COMPUTE(K, XR)                                                                   \
  do {                                                                                   \
    const unsigned short* wb = &wl[((K) & 1) * 12288];                                   \
    bf16x8 a0 = cvt8(XR[0], XR[1]);                                                      \
    bf16x8 a1 = cvt8(XR[2], XR[3]);                                                      \
    _Pragma("unroll")                                                                    \
    for (int cf = 0; cf < 12; ++cf) {                                                    \
      bf16x8 b0 = *(const bf16x8*)&wb[((cf >> 2) * 64 + (cf & 3) * 16 + l15) * 64 + c0]; \
      acc[cf] = __builtin_amdgcn_mfma_f32_16x16x32_bf16(a0, b0, acc[cf], 0, 0, 0);       \
    }                                                                                    \
    _Pragma("unroll")                                                                    \
    for (int cf = 0; cf < 12; ++cf) {                                                    \
      bf16x8 b1 = *(const bf16x8*)&wb[((cf >> 2) * 64 + (cf & 3) * 16 + l15) * 64 + c1]; \
      acc[cf] = __builtin_amdgcn_mfma_f32_16x16x32_bf16(a1, b1, acc[cf], 0, 0, 0);       \
    }                                                                                    \
  } while (0)

#define SB __builtin_amdgcn_sched_barrier(0)

#define ITER(K, XCUR, XPRE, VM)                                    \
  do {                                                             \
    if ((K) < 15) STAGE(((K) + 1) & 1, (K) + 1);                   \
    SB;                                                            \
    if ((K) < 14) XLOAD(XPRE, (K) + 2);                            \
    SB;                                                            \
    asm volatile("s_waitcnt vmcnt(" #VM ")" ::: "memory");         \
    SB;                                                            \
    __builtin_amdgcn_s_barrier();                                  \
    COMPUTE(K, XCUR);                                              \
    __builtin_amdgcn_s_barrier();                                  \
  } while (0)

  STAGE(0, 0);
  SB;
  XLOAD(xr0, 0);
  XLOAD(xr1, 1);
  SB;

  ITER(0, xr0, xr2, 14);
  ITER(1, xr1, xr0, 14);
  ITER(2, xr2, xr1, 14);
  ITER(3, xr0, xr2, 14);
  ITER(4, xr1, xr0, 14);
  ITER(5, xr2, xr1, 14);
  ITER(6, xr0, xr2, 14);
  ITER(7, xr1, xr0, 14);
  ITER(8, xr2, xr1, 14);
  ITER(9, xr0, xr2, 14);
  ITER(10, xr1, xr0, 14);
  ITER(11, xr2, xr1, 14);
  ITER(12, xr0, xr2, 14);
  ITER(13, xr1, xr0, 14);
  ITER(14, xr2, xr1, 10);
  ITER(15, xr0, xr2, 0);

#undef ITER
#undef COMPUTE
#undef XLOAD
#undef STAGE
#undef SB

#pragma unroll
  for (int cf = 0; cf < 4; ++cf) {
    int col = cf * 16 + l15;
#pragma unroll
    for (int r = 0; r < 4; ++r) {
      size_t row = (size_t)(r0 + w * 16 + lh * 4 + r);
      kb[row * HD_ + col] = f2bf(acc[cf][r]);
      qb[row * HD_ + col] = f2bf(acc[4 + cf][r]);
      vb[row * HD_ + col] = f2bf(acc[8 + cf][r]);
    }
  }
}

// ---------------- flash attention v2: 1 barrier/iter, dbuf LDS, issue-early loads ----------------
// scores already in exp2 domain (log2e folded into kb via wconv).
__global__ __launch_bounds__(256) void attn_kernel(const unsigned short* __restrict__ kb,
                                                   const unsigned short* __restrict__ qb,
                                                   const unsigned short* __restrict__ vb,
                                                   float* __restrict__ out) {
  __shared__ __align__(16) unsigned short q_lds[2][64 * 72];  // [s][d] padded
  __shared__ __align__(16) unsigned short v_lds[2][64 * 72];  // [d][s] padded (transposed)
  __shared__ __align__(16) unsigned short p_lds[64 * 72];     // [t][s] padded (same-wave only)

  const int tid = threadIdx.x;
  const int lane = tid & 63;
  const int w = tid >> 6;          // 4 waves x 16 query rows
  const int bid = blockIdx.x;
  // balanced mapping: per-CU pair (bid, bid+256) sums to 34 iters
  const int idx = bid >> 4;
  const int jt = (idx < 16) ? (31 - idx) : (idx - 16);
  const int b = bid & 15;
  const int t0 = jt * 64;
  const int l15 = lane & 15;
  const int lh = lane >> 4;
  const size_t base = (size_t)b * T_ * HD_;

  // staging coords
  const int qrow = tid >> 3, qc8 = tid & 7;       // q rows 0..31 (+32 for second chunk)
  const int vss = tid & 63, vd0 = (tid >> 6) * 8; // v: s=vss, d0 / d0+32

  // hoist k fragments (A operand; scale+log2e pre-folded), 2 d-halves
  bf16x8 kf[2];
#pragma unroll
  for (int ks = 0; ks < 2; ++ks)
    kf[ks] = *reinterpret_cast<const bf16x8*>(
        &kb[base + (size_t)(t0 + w * 16 + l15) * HD_ + ks * 32 + lh * 8]);

  // prologue: issue j=0 staging loads into regs
  bf16x8 qr0, qr1, vr0, vr1;
  qr0 = *reinterpret_cast<const bf16x8*>(&qb[base + (size_t)qrow * HD_ + qc8 * 8]);
  qr1 = *reinterpret_cast<const bf16x8*>(&qb[base + (size_t)(qrow + 32) * HD_ + qc8 * 8]);
  vr0 = *reinterpret_cast<const bf16x8*>(&vb[base + (size_t)vss * HD_ + vd0]);
  vr1 = *reinterpret_cast<const bf16x8*>(&vb[base + (size_t)vss * HD_ + vd0 + 32]);

  f32x4 o[4];
#pragma unroll
  for (int i = 0; i < 4; ++i) o[i] = {0.f, 0.f, 0.f, 0.f};
  float mrun[4], lrun[4];
#pragma unroll
  for (int r = 0; r < 4; ++r) { mrun[r] = -1e30f; lrun[r] = 0.f; }

  for (int j = 0; j <= jt; ++j) {
    const int buf = j & 1;
    // write staged regs to LDS (compiler inserts exact vmcnt waits)
    *reinterpret_cast<bf16x8*>(&q_lds[buf][qrow * 72 + qc8 * 8]) = qr0;
    *reinterpret_cast<bf16x8*>(&q_lds[buf][(qrow + 32) * 72 + qc8 * 8]) = qr1;
#pragma unroll
    for (int jj = 0; jj < 8; ++jj) v_lds[buf][(vd0 + jj) * 72 + vss] = (unsigned short)vr0[jj];
#pragma unroll
    for (int jj = 0; jj < 8; ++jj) v_lds[buf][(vd0 + 32 + jj) * 72 + vss] = (unsigned short)vr1[jj];
    __syncthreads();

    // issue next tile's loads — they fly under QK^T + softmax + PV
    if (j < jt) {
      const size_t sb = base + (size_t)(j + 1) * 64 * HD_;
      qr0 = *reinterpret_cast<const bf16x8*>(&qb[sb + (size_t)qrow * HD_ + qc8 * 8]);
      qr1 = *reinterpret_cast<const bf16x8*>(&qb[sb + (size_t)(qrow + 32) * HD_ + qc8 * 8]);
      vr0 = *reinterpret_cast<const bf16x8*>(&vb[sb + (size_t)vss * HD_ + vd0]);
      vr1 = *reinterpret_cast<const bf16x8*>(&vb[sb + (size_t)vss * HD_ + vd0 + 32]);
    }
    __builtin_amdgcn_sched_barrier(0);

    // S = K * Q^T  (16x64 per wave), exp2 domain
    f32x4 sf[4];
#pragma unroll
    for (int cf = 0; cf < 4; ++cf) sf[cf] = {0.f, 0.f, 0.f, 0.f};
    __builtin_amdgcn_s_setprio(1);
#pragma unroll
    for (int ks = 0; ks < 2; ++ks) {
#pragma unroll
      for (int cf = 0; cf < 4; ++cf) {
        bf16x8 bq = *reinterpret_cast<const bf16x8*>(&q_lds[buf][(cf * 16 + l15) * 72 + ks * 32 + lh * 8]);
        sf[cf] = __builtin_amdgcn_mfma_f32_16x16x32_bf16(kf[ks], bq, sf[cf], 0, 0, 0);
      }
    }
    __builtin_amdgcn_s_setprio(0);

    const bool diag = (j == jt);
    const int s0 = j * 64;
    float pv[4][4];
#pragma unroll
    for (int r = 0; r < 4; ++r) {
      const int tg = t0 + w * 16 + lh * 4 + r;
      float pm = -1e30f;
#pragma unroll
      for (int cf = 0; cf < 4; ++cf) {
        float v = sf[cf][r];
        if (diag && (s0 + cf * 16 + l15) > tg) v = -1e30f;
        pv[cf][r] = v;
        pm = fmaxf(pm, v);
      }
      pm = fmaxf(pm, __shfl_xor(pm, 1));
      pm = fmaxf(pm, __shfl_xor(pm, 2));
      pm = fmaxf(pm, __shfl_xor(pm, 4));
      pm = fmaxf(pm, __shfl_xor(pm, 8));
      float mn = fmaxf(mrun[r], pm);
      float scl = exp2f(mrun[r] - mn);
      mrun[r] = mn;
      float rs = 0.f;
#pragma unroll
      for (int cf = 0; cf < 4; ++cf) {
        float e = exp2f(pv[cf][r] - mn);
        pv[cf][r] = e;
        rs += e;
      }
      rs += __shfl_xor(rs, 1);
      rs += __shfl_xor(rs, 2);
      rs += __shfl_xor(rs, 4);
      rs += __shfl_xor(rs, 8);
      lrun[r] = lrun[r] * scl + rs;
#pragma unroll
      for (int df = 0; df < 4; ++df) o[df][r] *= scl;
    }
    // P -> LDS (same-wave region: no barrier needed, lgkmcnt handles RAW)
#pragma unroll
    for (int cf = 0; cf < 4; ++cf)
#pragma unroll
      for (int r = 0; r < 4; ++r)
        p_lds[(w * 16 + lh * 4 + r) * 72 + cf * 16 + l15] = f2bf(pv[cf][r]);

    // O += P * V
    __builtin_amdgcn_s_setprio(1);
#pragma unroll
    for (int ks = 0; ks < 2; ++ks) {
      bf16x8 pa = *reinterpret_cast<const bf16x8*>(&p_lds[(w * 16 + l15) * 72 + ks * 32 + lh * 8]);
#pragma unroll
      for (int df = 0; df < 4; ++df) {
        bf16x8 bv = *reinterpret_cast<const bf16x8*>(&v_lds[buf][(df * 16 + l15) * 72 + ks * 32 + lh * 8]);
        o[df] = __builtin_amdgcn_mfma_f32_16x16x32_bf16(pa, bv, o[df], 0, 0, 0);
      }
    }
    __builtin_amdgcn_s_setprio(0);
  }

#pragma unroll
  for (int r = 0; r < 4; ++r) {
    float inv = 1.f / lrun[r];
    int row = t0 + w * 16 + lh * 4 + r;
#pragma unroll
    for (int df = 0; df < 4; ++df)
      out[base + (size_t)row * HD_ + df * 16 + l15] = o[df][r] * inv;
  }
}

extern "C" void kernel_launch(void* const* d_in, const int* in_sizes, int n_in,
                              void* d_out, int out_size, void* d_ws, size_t ws_size,
                              hipStream_t stream) {
  const float* x  = (const float*)d_in[0];
  const float* Wk = (const float*)d_in[1];
  const float* Wq = (const float*)d_in[2];
  const float* Wv = (const float*)d_in[3];
  float* out = (float*)d_out;

  char* ws = (char*)d_ws;
  unsigned short* wt2 = (unsigned short*)ws;                                 // 384 KB
  unsigned short* kb = (unsigned short*)(ws + 524288);                       // 4 MB
  unsigned short* qb = (unsigned short*)(ws + 524288 + 4 * 1024 * 1024);     // 4 MB
  unsigned short* vb = (unsigned short*)(ws + 524288 + 8 * 1024 * 1024);     // 4 MB

  hipLaunchKernelGGL(wconv_kernel, dim3(768), dim3(256), 0, stream, Wk, Wq, Wv, wt2);
  hipLaunchKernelGGL(qkv_kernel, dim3(512), dim3(256), 0, stream, x, wt2, kb, qb, vb);
  hipLaunchKernelGGL(attn_kernel, dim3(512), dim3(256), 0, stream, kb, qb, vb, out);
}